// Round 2
// baseline (73.871 us; speedup 1.0000x reference)
//
#include <hip/hip_runtime.h>
#include <math.h>

#define BB   4
#define NN   4096
#define DD   128
#define NCLS 5
#define SS   800      // (N - NQ) / NCLS
#define KK   400      // int(0.5 * S)
#define NQ   96
#define MM   (NCLS*KK + NQ)   // 2096
#define NSUP (NCLS*SS)        // 4000

// ---------------- scores: f64 dot, then exact f32 sigmoid composition ----------------
// s32 replicates numpy's f32 pipeline with correctly-rounded steps:
//   z32 = round32(exact dot); u = (z32+b)/100 [f32]; e = round32(exp(-u));
//   t = 1+e [f32]; s = 1/t [f32]
__global__ void score_kernel(const float* __restrict__ X, const float* __restrict__ W,
                             const float* __restrict__ bias,
                             float* __restrict__ scoreF) {
    int row  = blockIdx.x * 4 + (threadIdx.x >> 6);   // 4 waves / block
    int lane = threadIdx.x & 63;
    if (row >= BB * NN) return;
    const float* x = X + (size_t)row * DD;
    double acc = (double)x[lane]      * (double)W[lane]
               + (double)x[lane + 64] * (double)W[lane + 64];
    #pragma unroll
    for (int off = 32; off > 0; off >>= 1) acc += __shfl_down(acc, off);
    if (lane == 0) {
        float z32 = (float)acc;
        float u   = (z32 + bias[0]) / 100.0f;   // IEEE f32 divide (no fast-math)
        float e   = (float)exp(-(double)u);     // correctly-rounded f32 exp
        float t   = 1.0f + e;
        float s   = 1.0f / t;
        scoreF[row] = s;
    }
}

// ---------------- per-(b,class) top-400: bitonic sort of packed (score,~idx) keys ----------------
// key = (f32 score bits << 32) | (1023 - local_idx). Scores are in (0,1) so the
// sign bit is 0 and uint order == float order. Descending key sort gives
// descending score with ascending index on f32 ties (jax.lax.top_k / stable-np order).
__global__ void __launch_bounds__(512)
topk_kernel(const float* __restrict__ scoreF, int* __restrict__ gidx, float* __restrict__ gvals) {
    __shared__ unsigned long long kv[1024];
    const int b = blockIdx.x / NCLS;
    const int c = blockIdx.x % NCLS;
    const int t = threadIdx.x;

    const float* sc = scoreF + (size_t)b * NN + c * SS;
    for (int i = t; i < 1024; i += 512) {
        if (i < SS) {
            unsigned int sb = __float_as_uint(sc[i]);
            kv[i] = ((unsigned long long)sb << 32) | (unsigned int)(1023 - i);
        } else {
            kv[i] = 0ull;   // pad sinks (real keys have score bits ~0.5 in high word)
        }
    }
    __syncthreads();

    for (int k = 2; k <= 1024; k <<= 1) {
        for (int j = k >> 1; j > 0; j >>= 1) {
            for (int i = t; i < 1024; i += 512) {
                int ixj = i ^ j;
                if (ixj > i) {
                    unsigned long long a = kv[i], bb2 = kv[ixj];
                    bool aFirst = (a > bb2);                 // descending
                    bool descRegion = ((i & k) == 0);
                    if (descRegion ? (!aFirst) : aFirst) { kv[i] = bb2; kv[ixj] = a; }
                }
            }
            __syncthreads();
        }
    }

    for (int r = t; r < KK; r += 512) {
        unsigned long long k = kv[r];
        int li = 1023 - (int)(k & 0xFFFFFFFFull);
        int gi = c * SS + li;
        int m  = c * KK + r;
        gidx [b * MM + m] = gi;
        gvals[b * MM + m] = __uint_as_float((unsigned int)(k >> 32));
    }
    if (c == 0) {
        for (int q = t; q < NQ; q += 512) {
            int m  = NCLS * KK + q;
            int gi = NSUP + q;
            gidx [b * MM + m] = gi;
            gvals[b * MM + m] = scoreF[(size_t)b * NN + gi];
        }
    }
}

// ---------------- new_X = X[idx] * vals ; idx output as float ----------------
__global__ void newx_kernel(const float* __restrict__ X, const int* __restrict__ gidx,
                            const float* __restrict__ gvals,
                            float* __restrict__ outX, float* __restrict__ outIdx) {
    int bm = blockIdx.x;            // b*MM + m
    int d  = threadIdx.x;           // 128 threads
    int gi = gidx[bm];
    float v = gvals[bm];
    int b  = bm / MM;
    outX[(size_t)bm * DD + d] = X[((size_t)b * NN + gi) * DD + d] * v;
    if (d == 0) outIdx[bm] = (float)gi;
}

// ---------------- new_A = A[b, idx_i, idx_j] ----------------
__global__ void __launch_bounds__(256)
newa_kernel(const float* __restrict__ A, const int* __restrict__ gidx,
            float* __restrict__ outA) {
    __shared__ int cidx[MM];
    int bm = blockIdx.x;            // b*MM + i
    int b  = bm / MM;
    const int* gb = gidx + b * MM;
    for (int j = threadIdx.x; j < MM; j += 256) cidx[j] = gb[j];
    __syncthreads();
    int ri = gidx[bm];
    const float* arow = A + ((size_t)b * NN + ri) * NN;
    float* orow = outA + (size_t)bm * MM;
    for (int j = threadIdx.x; j < MM; j += 256) orow[j] = arow[cidx[j]];
}

extern "C" void kernel_launch(void* const* d_in, const int* in_sizes, int n_in,
                              void* d_out, int out_size, void* d_ws, size_t ws_size,
                              hipStream_t stream) {
    const float* A  = (const float*)d_in[0];
    const float* X  = (const float*)d_in[1];
    const float* W  = (const float*)d_in[2];
    const float* bi = (const float*)d_in[3];

    float* outA   = (float*)d_out;                         // B*M*M
    float* outX   = outA + (size_t)BB * MM * MM;           // B*M*D
    float* outIdx = outX + (size_t)BB * MM * DD;           // B*M

    char* ws = (char*)d_ws;
    float* scoreF = (float*)ws;                                 // B*N*4 = 65536
    int*   gidx   = (int*)  (ws + 65536);                       // B*M*4 = 33536
    float* gvals  = (float*)(ws + 65536 + 33536);               // B*M*4 = 33536

    score_kernel<<<(BB * NN) / 4, 256, 0, stream>>>(X, W, bi, scoreF);
    topk_kernel<<<BB * NCLS, 512, 0, stream>>>(scoreF, gidx, gvals);
    newx_kernel<<<BB * MM, DD, 0, stream>>>(X, gidx, gvals, outX, outIdx);
    newa_kernel<<<BB * MM, 256, 0, stream>>>(A, gidx, outA);
}

// Round 3
// 57.973 us; speedup vs baseline: 1.2742x; 1.2742x over previous
//
#include <hip/hip_runtime.h>
#include <math.h>

#define BB   4
#define NN   4096
#define DD   128
#define NCLS 5
#define SS   800      // (N - NQ) / NCLS
#define KK   400      // int(0.5 * S)
#define NQ   96
#define MM   (NCLS*KK + NQ)   // 2096
#define NSUP (NCLS*SS)        // 4000

// ---------------- scores: f64 dot, exact f32 sigmoid composition (verified R2, DO NOT TOUCH) ----------------
__global__ void score_kernel(const float* __restrict__ X, const float* __restrict__ W,
                             const float* __restrict__ bias,
                             float* __restrict__ scoreF) {
    int row  = blockIdx.x * 4 + (threadIdx.x >> 6);   // 4 waves / block
    int lane = threadIdx.x & 63;
    if (row >= BB * NN) return;
    const float* x = X + (size_t)row * DD;
    double acc = (double)x[lane]      * (double)W[lane]
               + (double)x[lane + 64] * (double)W[lane + 64];
    #pragma unroll
    for (int off = 32; off > 0; off >>= 1) acc += __shfl_down(acc, off);
    if (lane == 0) {
        float z32 = (float)acc;
        float u   = (z32 + bias[0]) / 100.0f;
        float e   = (float)exp(-(double)u);
        float t   = 1.0f + e;
        float s   = 1.0f / t;
        scoreF[row] = s;
    }
}

// ---------------- top-400 per (b,class): register bitonic, shfl for j<64, LDS only j>=64 ----------------
// key = (f32 score bits << 32) | (1023 - local_idx); full descending sort of 1024.
// Identical ordering to verified R2 sort; only the exchange mechanism changed.
__global__ void __launch_bounds__(1024)
topk_kernel(const float* __restrict__ scoreF, int* __restrict__ gidx, float* __restrict__ gvals) {
    __shared__ unsigned long long buf[2][1024];
    const int b = blockIdx.x / NCLS;
    const int c = blockIdx.x % NCLS;
    const int t = threadIdx.x;

    // queries (independent of sort): block c==0, threads 512..607
    if (c == 0 && t >= 512 && t < 512 + NQ) {
        int q  = t - 512;
        int gi = NSUP + q;
        int m  = NCLS * KK + q;
        gidx [b * MM + m] = gi;
        gvals[b * MM + m] = scoreF[(size_t)b * NN + gi];
    }

    const float* sc = scoreF + (size_t)b * NN + c * SS;
    unsigned long long v = 0ull;    // pad sinks; real keys have high word ~0x3F00_0000
    if (t < SS)
        v = ((unsigned long long)__float_as_uint(sc[t]) << 32) | (unsigned int)(1023 - t);

    int p = 0;
    for (int k = 2; k <= 1024; k <<= 1) {
        for (int j = k >> 1; j > 0; j >>= 1) {
            unsigned long long o;
            if (j >= 64) {
                buf[p][t] = v;
                __syncthreads();
                o = buf[p][t ^ j];
                p ^= 1;
                // safe: next write to this buffer is 2 stages away, past another barrier
            } else {
                unsigned int lo = __shfl_xor((unsigned int)(v & 0xFFFFFFFFu), j);
                unsigned int hi = __shfl_xor((unsigned int)(v >> 32), j);
                o = ((unsigned long long)hi << 32) | lo;
            }
            // descending region ((t&k)==0): low slot keeps max
            bool keepMax = (((t & k) == 0) == ((t & j) == 0));
            v = keepMax ? (v > o ? v : o) : (v < o ? v : o);
        }
    }

    if (t < KK) {
        int li = 1023 - (int)(v & 0xFFFFFFFFull);
        gidx [b * MM + c * KK + t] = c * SS + li;
        gvals[b * MM + c * KK + t] = __uint_as_float((unsigned int)(v >> 32));
    }
}

// ---------------- fused: new_A row gather + new_X row + idx (as float) ----------------
__global__ void __launch_bounds__(256)
newxa_kernel(const float* __restrict__ A, const float* __restrict__ X,
             const int* __restrict__ gidx, const float* __restrict__ gvals,
             float* __restrict__ outA, float* __restrict__ outX, float* __restrict__ outIdx) {
    __shared__ int cidx[MM];
    const int bm = blockIdx.x;            // b*MM + i
    const int b  = bm / MM;
    const int* gb = gidx + b * MM;
    for (int j = threadIdx.x; j < MM; j += 256) cidx[j] = gb[j];
    __syncthreads();

    const int ri = cidx[bm - b * MM];

    if (threadIdx.x < DD) {
        float vscale = gvals[bm];
        outX[(size_t)bm * DD + threadIdx.x] =
            X[((size_t)b * NN + ri) * DD + threadIdx.x] * vscale;
        if (threadIdx.x == 0) outIdx[bm] = (float)ri;
    }

    const float* arow = A + ((size_t)b * NN + ri) * NN;
    float* orow = outA + (size_t)bm * MM;
    // MM = 2096 = 4*524; orow 16B-aligned -> float4 stores
    for (int jj = threadIdx.x * 4; jj < MM; jj += 1024) {
        float4 vv;
        vv.x = arow[cidx[jj]];
        vv.y = arow[cidx[jj + 1]];
        vv.z = arow[cidx[jj + 2]];
        vv.w = arow[cidx[jj + 3]];
        *(float4*)(orow + jj) = vv;
    }
}

extern "C" void kernel_launch(void* const* d_in, const int* in_sizes, int n_in,
                              void* d_out, int out_size, void* d_ws, size_t ws_size,
                              hipStream_t stream) {
    const float* A  = (const float*)d_in[0];
    const float* X  = (const float*)d_in[1];
    const float* W  = (const float*)d_in[2];
    const float* bi = (const float*)d_in[3];

    float* outA   = (float*)d_out;                         // B*M*M
    float* outX   = outA + (size_t)BB * MM * MM;           // B*M*D
    float* outIdx = outX + (size_t)BB * MM * DD;           // B*M

    char* ws = (char*)d_ws;
    float* scoreF = (float*)ws;                                 // B*N*4 = 65536
    int*   gidx   = (int*)  (ws + 65536);                       // B*M*4 = 33536
    float* gvals  = (float*)(ws + 65536 + 33536);               // B*M*4 = 33536

    score_kernel<<<(BB * NN) / 4, 256, 0, stream>>>(X, W, bi, scoreF);
    topk_kernel<<<BB * NCLS, 1024, 0, stream>>>(scoreF, gidx, gvals);
    newxa_kernel<<<BB * MM, 256, 0, stream>>>(A, X, gidx, gvals, outA, outX, outIdx);
}